// Round 1
// baseline (2129.507 us; speedup 1.0000x reference)
//
#include <hip/hip_runtime.h>
#include <math.h>

typedef unsigned short u16;
typedef __attribute__((ext_vector_type(8))) u16 u16x8;
typedef __attribute__((ext_vector_type(8))) __bf16 b16x8;
typedef __attribute__((ext_vector_type(4))) float f32x4;

#define DEV __device__ __forceinline__

namespace {

constexpr int Tc = 8192, Dc = 1024, Fc = 4096, Ec = 8;

DEV u16 f2bf(float f){ union{float f; unsigned u;} v; v.f=f; unsigned r = v.u + 0x7fffu + ((v.u>>16)&1u); return (u16)(r>>16); }
DEV float bf2f(u16 h){ union{unsigned u; float f;} v; v.u=((unsigned)h)<<16; return v.f; }
DEV f32x4 zero4(){ f32x4 z = {0.f,0.f,0.f,0.f}; return z; }
DEV f32x4 mfma16(u16x8 a, u16x8 b, f32x4 c){
  union { u16x8 u; b16x8 b; } ua, ub; ua.u = a; ub.u = b;
  return __builtin_amdgcn_mfma_f32_16x16x32_bf16(ua.b, ub.b, c, 0, 0, 0);
}
DEV float gelu_exact(float v){ return 0.5f*v*(1.0f + erff(v*0.70710678118654752f)); }

// ---------------- prep kernels ----------------
__global__ __launch_bounds__(256) void split_x_k(const float* __restrict__ x, u16* __restrict__ hi, u16* __restrict__ lo){
  size_t i = (size_t)blockIdx.x*256 + threadIdx.x;
  #pragma unroll
  for (int r=0;r<8;r++){
    size_t idx = i + (size_t)r*1048576;
    float v = x[idx];
    u16 h = f2bf(v);
    hi[idx] = h;
    lo[idx] = f2bf(v - bf2f(h));
  }
}

__global__ __launch_bounds__(256) void concat_bias_k(const float* __restrict__ bq, const float* __restrict__ bk,
                                                     const float* __restrict__ bv, float* __restrict__ dst){
  int n = blockIdx.x*256 + threadIdx.x;
  if (n < 3072) dst[n] = (n<1024) ? bq[n] : ((n<2048) ? bk[n-1024] : bv[n-2048]);
}

// W[Kd][Nd] f32 -> out[Nd][Kd] bf16 hi (+lo if oLo)
__global__ __launch_bounds__(256) void transpose_split_k(const float* __restrict__ W, u16* __restrict__ oHi, u16* __restrict__ oLo,
                                                         int Kd, int Nd, size_t inStride, size_t outStride){
  __shared__ float t[32][33];
  int e = blockIdx.z;
  W += (size_t)e*inStride; oHi += (size_t)e*outStride; if (oLo) oLo += (size_t)e*outStride;
  int k0 = blockIdx.x*32, n0 = blockIdx.y*32;
  int c = threadIdx.x & 31, r0 = threadIdx.x >> 5;
  #pragma unroll
  for (int i=0;i<4;i++){ int r = r0 + i*8; t[r][c] = W[(size_t)(k0+r)*Nd + n0 + c]; }
  __syncthreads();
  #pragma unroll
  for (int i=0;i<4;i++){
    int r = r0 + i*8;
    float v = t[c][r];                    // = W[k0+c][n0+r]
    size_t oidx = (size_t)(n0+r)*Kd + k0 + c;
    u16 h = f2bf(v);
    oHi[oidx] = h;
    if (oLo) oLo[oidx] = f2bf(v - bf2f(h));
  }
}

// ---------------- GEMM: C[M][N] = A[M][K] @ Bt[N][K]^T ----------------
// MODE 0: QKV (x3, bias, scatter to [3][B][H][S][64] hi/lo)
// MODE 1: out-proj (x3, bias, f32 out)
// MODE 2: FF1 per-expert (bf16, bias+gelu, bf16 out)
// MODE 3: FF2 per-expert (bf16, bias, bf16 out)
template<int MODE>
__global__ __launch_bounds__(256,2) void gemm_k(
    const u16* __restrict__ Ahi, const u16* __restrict__ Alo,
    const u16* __restrict__ Bhi, const u16* __restrict__ Blo,
    const float* __restrict__ bias,
    float* __restrict__ outF, u16* __restrict__ outHi, u16* __restrict__ outLo,
    const int* __restrict__ offsets,
    int N, int K, int lda, int ldb)
{
  constexpr bool X3 = (MODE <= 1);
  constexpr int PL = X3 ? 2 : 1;
  int Me = 0, rowbase = 0;
  if constexpr (MODE >= 2){
    int e = blockIdx.z;
    rowbase = offsets[e];
    Me = offsets[e+1] - rowbase;
    if ((int)blockIdx.x*128 >= Me) return;     // uniform early exit
    Ahi += (size_t)rowbase * lda;
    Bhi += (size_t)e * N * K;
    bias += (size_t)e * N;
  }
  __shared__ u16 sA[PL][128*40];   // pitch 40 (=80B, 16B aligned, ~2-way banks)
  __shared__ u16 sB[PL][128*40];
  const int tid = threadIdx.x;
  const int lane = tid & 63, wid = tid >> 6;
  const int l15 = lane & 15, l4 = lane >> 4;
  const int mh = (wid >> 1) * 64, nh = (wid & 1) * 64;
  const int bm = blockIdx.x, bn = blockIdx.y;

  f32x4 acc[4][4];
  #pragma unroll
  for (int i=0;i<4;i++)
    #pragma unroll
    for (int j=0;j<4;j++) acc[i][j] = zero4();

  const int nK = K >> 5;
  for (int kb=0; kb<nK; ++kb){
    const int k0 = kb << 5;
    __syncthreads();
    #pragma unroll
    for (int r2=0;r2<2;r2++){
      int c = tid + r2*256;                   // 512 chunks of 8 bf16
      int row = c >> 2, k8 = (c & 3) * 8;
      size_t ga = (size_t)(bm*128 + row)*lda + k0 + k8;
      size_t gb = (size_t)(bn*128 + row)*ldb + k0 + k8;
      *(u16x8*)&sA[0][row*40 + k8] = *(const u16x8*)(Ahi + ga);
      *(u16x8*)&sB[0][row*40 + k8] = *(const u16x8*)(Bhi + gb);
      if constexpr (X3){
        *(u16x8*)&sA[1][row*40 + k8] = *(const u16x8*)(Alo + ga);
        *(u16x8*)&sB[1][row*40 + k8] = *(const u16x8*)(Blo + gb);
      }
    }
    __syncthreads();
    u16x8 af[PL][4], bfr[PL][4];
    #pragma unroll
    for (int mt=0;mt<4;mt++){
      int ra = (mh + mt*16 + l15)*40 + l4*8;
      int rb = (nh + mt*16 + l15)*40 + l4*8;
      af[0][mt]  = *(const u16x8*)&sA[0][ra];
      bfr[0][mt] = *(const u16x8*)&sB[0][rb];
      if constexpr (X3){ af[1][mt] = *(const u16x8*)&sA[1][ra]; bfr[1][mt] = *(const u16x8*)&sB[1][rb]; }
    }
    #pragma unroll
    for (int mt=0;mt<4;mt++)
      #pragma unroll
      for (int nt=0;nt<4;nt++){
        acc[mt][nt] = mfma16(af[0][mt], bfr[0][nt], acc[mt][nt]);
        if constexpr (X3){
          acc[mt][nt] = mfma16(af[0][mt], bfr[1][nt], acc[mt][nt]);   // hi*lo
          acc[mt][nt] = mfma16(af[1][mt], bfr[0][nt], acc[mt][nt]);   // lo*hi
        }
      }
  }
  #pragma unroll
  for (int mt=0;mt<4;mt++)
    #pragma unroll
    for (int nt=0;nt<4;nt++)
      #pragma unroll
      for (int r=0;r<4;r++){
        int m = bm*128 + mh + mt*16 + l4*4 + r;     // C/D: row=(lane>>4)*4+reg
        int n = bn*128 + nh + nt*16 + l15;          //      col=lane&15
        float v = acc[mt][nt][r];
        if constexpr (MODE == 0){
          v += bias[n];
          int which = n >> 10, h = (n >> 6) & 15, d = n & 63;
          int b = m >> 11, s = m & 2047;
          size_t idx = ((((size_t)which*4 + b)*16 + h)*2048 + s)*64 + d;
          u16 hi = f2bf(v);
          outHi[idx] = hi; outLo[idx] = f2bf(v - bf2f(hi));
        } else if constexpr (MODE == 1){
          outF[(size_t)m*1024 + n] = v + bias[n];
        } else if constexpr (MODE == 2){
          if (m < Me){
            float g = gelu_exact(v + bias[n]);
            outHi[(size_t)(rowbase + m)*N + n] = f2bf(g);
          }
        } else {
          if (m < Me){
            outHi[(size_t)(rowbase + m)*N + n] = f2bf(v + bias[n]);
          }
        }
      }
}

// ---------------- flash attention, bf16x3 ----------------
// grid (S/64, B*H); block 256 = 4 waves, wave owns 16 q-rows; KV tile 64.
__global__ __launch_bounds__(256,2) void flash_k(
    const u16* __restrict__ qhi, const u16* __restrict__ qlo,
    const u16* __restrict__ khi, const u16* __restrict__ klo,
    const u16* __restrict__ vhi, const u16* __restrict__ vlo,
    u16* __restrict__ ohi, u16* __restrict__ olo)
{
  __shared__ u16 Kl[2][64*72];   // [plane][kk][d] pitch 72
  __shared__ u16 Vt[2][64*72];   // [plane][d][kk] pitch 72 (transposed)
  __shared__ u16 Pl[2][64*72];   // [plane][q][kk] pitch 72
  const int qt = blockIdx.x, bh = blockIdx.y;
  const int b = bh >> 4, h = bh & 15;
  const int tid = threadIdx.x, wid = tid >> 6, lane = tid & 63;
  const int l15 = lane & 15, l4 = lane >> 4;
  const size_t bhBase = (size_t)bh * (2048*64);

  u16x8 qf[2][2];                 // [plane][kstep]
  #pragma unroll
  for (int ks=0;ks<2;ks++){
    size_t po = bhBase + (size_t)(qt*64 + wid*16 + l15)*64 + ks*32 + l4*8;
    qf[0][ks] = *(const u16x8*)(qhi + po);
    qf[1][ks] = *(const u16x8*)(qlo + po);
  }
  f32x4 O[4];
  #pragma unroll
  for (int nd=0;nd<4;nd++) O[nd] = zero4();
  float mrow[4], lrow[4];
  #pragma unroll
  for (int r=0;r<4;r++){ mrow[r] = -1e30f; lrow[r] = 0.f; }

  for (int t=0;t<32;++t){
    __syncthreads();                              // protect K/V restage vs prior reads
    const size_t kvBase = bhBase + (size_t)t*(64*64);
    #pragma unroll
    for (int pl=0; pl<2; ++pl){
      const u16* ks_ = pl ? klo : khi;
      const u16* vs_ = pl ? vlo : vhi;
      #pragma unroll
      for (int r2=0;r2<2;r2++){
        int c = tid + r2*256;
        int kk = c >> 3, c8 = (c & 7) * 8;
        *(u16x8*)&Kl[pl][kk*72 + c8] = *(const u16x8*)(ks_ + kvBase + (size_t)kk*64 + c8);
      }
      #pragma unroll
      for (int r2=0;r2<2;r2++){
        int c = tid + r2*256;
        int kk = c >> 3, d0 = (c & 7) * 8;
        u16x8 vv = *(const u16x8*)(vs_ + kvBase + (size_t)kk*64 + d0);
        #pragma unroll
        for (int j=0;j<8;j++) Vt[pl][(d0+j)*72 + kk] = vv[j];
      }
    }
    __syncthreads();

    f32x4 sc[4];
    #pragma unroll
    for (int nt=0;nt<4;nt++){
      u16x8 kf[2][2];
      #pragma unroll
      for (int pl=0;pl<2;pl++)
        #pragma unroll
        for (int ks=0;ks<2;ks++)
          kf[pl][ks] = *(const u16x8*)&Kl[pl][(nt*16 + l15)*72 + ks*32 + l4*8];
      f32x4 a = zero4();
      a = mfma16(qf[0][0], kf[0][0], a);
      a = mfma16(qf[0][1], kf[0][1], a);
      a = mfma16(qf[0][0], kf[1][0], a);
      a = mfma16(qf[0][1], kf[1][1], a);
      a = mfma16(qf[1][0], kf[0][0], a);
      a = mfma16(qf[1][1], kf[0][1], a);
      sc[nt] = a;
    }
    float alpha[4];
    #pragma unroll
    for (int r=0;r<4;r++){
      float mx = -1e30f;
      #pragma unroll
      for (int nt=0;nt<4;nt++){ sc[nt][r] *= 0.125f; mx = fmaxf(mx, sc[nt][r]); }
      #pragma unroll
      for (int sh=1; sh<16; sh<<=1) mx = fmaxf(mx, __shfl_xor(mx, sh, 64));
      float mn = fmaxf(mrow[r], mx);
      alpha[r] = __expf(mrow[r] - mn);
      mrow[r] = mn;
      float ls = 0.f;
      #pragma unroll
      for (int nt=0;nt<4;nt++){
        float p = __expf(sc[nt][r] - mn);
        sc[nt][r] = p;
        ls += p;
      }
      #pragma unroll
      for (int sh=1; sh<16; sh<<=1) ls += __shfl_xor(ls, sh, 64);
      lrow[r] = lrow[r]*alpha[r] + ls;
    }
    // P: C-layout regs -> LDS (hi/lo). Per-wave rows only; same-wave RAW handled by lgkmcnt.
    #pragma unroll
    for (int nt=0;nt<4;nt++)
      #pragma unroll
      for (int r=0;r<4;r++){
        int row = wid*16 + l4*4 + r;
        int col = nt*16 + l15;
        float p = sc[nt][r];
        u16 hi = f2bf(p);
        Pl[0][row*72 + col] = hi;
        Pl[1][row*72 + col] = f2bf(p - bf2f(hi));
      }
    #pragma unroll
    for (int nd=0;nd<4;nd++)
      #pragma unroll
      for (int r=0;r<4;r++) O[nd][r] *= alpha[r];
    u16x8 pf[2][2];
    #pragma unroll
    for (int pl=0;pl<2;pl++)
      #pragma unroll
      for (int ks=0;ks<2;ks++)
        pf[pl][ks] = *(const u16x8*)&Pl[pl][(wid*16 + l15)*72 + ks*32 + l4*8];
    #pragma unroll
    for (int nd=0;nd<4;nd++){
      u16x8 vf[2][2];
      #pragma unroll
      for (int pl=0;pl<2;pl++)
        #pragma unroll
        for (int ks=0;ks<2;ks++)
          vf[pl][ks] = *(const u16x8*)&Vt[pl][(nd*16 + l15)*72 + ks*32 + l4*8];
      f32x4 a = O[nd];
      a = mfma16(pf[0][0], vf[0][0], a);
      a = mfma16(pf[0][1], vf[0][1], a);
      a = mfma16(pf[0][0], vf[1][0], a);
      a = mfma16(pf[0][1], vf[1][1], a);
      a = mfma16(pf[1][0], vf[0][0], a);
      a = mfma16(pf[1][1], vf[0][1], a);
      O[nd] = a;
    }
  }
  #pragma unroll
  for (int nd=0;nd<4;nd++)
    #pragma unroll
    for (int r=0;r<4;r++){
      int srow = qt*64 + wid*16 + l4*4 + r;
      int d = nd*16 + l15;
      float v = O[nd][r] / lrow[r];
      size_t idx = ((size_t)b*2048 + srow)*1024 + h*64 + d;   // [B,S,H*64] token-major
      u16 hi = f2bf(v);
      ohi[idx] = hi; olo[idx] = f2bf(v - bf2f(hi));
    }
}

// ---------------- LayerNorms ----------------
__global__ __launch_bounds__(256) void ln1_k(const float* __restrict__ y1, const float* __restrict__ x,
                                             const float* __restrict__ g, const float* __restrict__ be,
                                             float* __restrict__ x1, u16* __restrict__ x1b){
  __shared__ float red[2][4];
  int t = blockIdx.x, tid = threadIdx.x;
  const float* yr = y1 + (size_t)t*1024;
  const float* xr = x + (size_t)t*1024;
  float v[4], s = 0.f, s2 = 0.f;
  #pragma unroll
  for (int i=0;i<4;i++){ int d = tid + i*256; v[i] = yr[d] + xr[d]; s += v[i]; s2 += v[i]*v[i]; }
  #pragma unroll
  for (int sh=1; sh<64; sh<<=1){ s += __shfl_xor(s, sh, 64); s2 += __shfl_xor(s2, sh, 64); }
  int wid = tid >> 6, lane = tid & 63;
  if (lane == 0){ red[0][wid] = s; red[1][wid] = s2; }
  __syncthreads();
  s  = red[0][0]+red[0][1]+red[0][2]+red[0][3];
  s2 = red[1][0]+red[1][1]+red[1][2]+red[1][3];
  float mu = s * (1.f/1024.f);
  float var = s2 * (1.f/1024.f) - mu*mu;
  float inv = 1.0f / sqrtf(var + 1e-5f);
  #pragma unroll
  for (int i=0;i<4;i++){
    int d = tid + i*256;
    float o2 = (v[i]-mu)*inv*g[d] + be[d];
    x1[(size_t)t*1024 + d] = o2;
    x1b[(size_t)t*1024 + d] = f2bf(o2);
  }
}

__global__ __launch_bounds__(256) void ln2_k(const float* __restrict__ x1, const u16* __restrict__ ybuf,
                                             const int* __restrict__ tok_slot, const float* __restrict__ tok_wt,
                                             const float* __restrict__ g, const float* __restrict__ be,
                                             float* __restrict__ out){
  __shared__ float red[2][4];
  int t = blockIdx.x, tid = threadIdx.x;
  int s0 = tok_slot[t*2], s1 = tok_slot[t*2+1];
  float w0 = tok_wt[t*2], w1 = tok_wt[t*2+1];
  const float* xr = x1 + (size_t)t*1024;
  const u16* y0 = ybuf + (size_t)s0*1024;
  const u16* y1p = ybuf + (size_t)s1*1024;
  float v[4], s = 0.f, s2 = 0.f;
  #pragma unroll
  for (int i=0;i<4;i++){
    int d = tid + i*256;
    v[i] = xr[d] + w0*bf2f(y0[d]) + w1*bf2f(y1p[d]);
    s += v[i]; s2 += v[i]*v[i];
  }
  #pragma unroll
  for (int sh=1; sh<64; sh<<=1){ s += __shfl_xor(s, sh, 64); s2 += __shfl_xor(s2, sh, 64); }
  int wid = tid >> 6, lane = tid & 63;
  if (lane == 0){ red[0][wid] = s; red[1][wid] = s2; }
  __syncthreads();
  s  = red[0][0]+red[0][1]+red[0][2]+red[0][3];
  s2 = red[1][0]+red[1][1]+red[1][2]+red[1][3];
  float mu = s * (1.f/1024.f);
  float var = s2 * (1.f/1024.f) - mu*mu;
  float inv = 1.0f / sqrtf(var + 1e-5f);
  #pragma unroll
  for (int i=0;i<4;i++){
    int d = tid + i*256;
    out[(size_t)t*1024 + d] = (v[i]-mu)*inv*g[d] + be[d];
  }
}

// ---------------- routing ----------------
__global__ __launch_bounds__(256) void gate_k(const float* __restrict__ x1, const float* __restrict__ gW, const float* __restrict__ gb,
                                              int* __restrict__ tok_e, float* __restrict__ tok_wt,
                                              int* __restrict__ counts, float* __restrict__ probsum){
  __shared__ float psum[8];
  __shared__ int pcnt[8];
  int tid = threadIdx.x, wid = tid>>6, lane = tid&63;
  if (tid < 8){ psum[tid] = 0.f; pcnt[tid] = 0; }
  __syncthreads();
  for (int it=0; it<8; ++it){
    int t = blockIdx.x*32 + wid*8 + it;
    const float* xr = x1 + (size_t)t*1024;
    float a0=0,a1=0,a2=0,a3=0,a4=0,a5=0,a6=0,a7=0;
    #pragma unroll
    for (int j=0;j<16;j++){
      int i = lane + j*64;
      float xv = xr[i];
      const float4* w4 = (const float4*)(gW + (size_t)i*8);
      float4 wa = w4[0], wb = w4[1];
      a0 += xv*wa.x; a1 += xv*wa.y; a2 += xv*wa.z; a3 += xv*wa.w;
      a4 += xv*wb.x; a5 += xv*wb.y; a6 += xv*wb.z; a7 += xv*wb.w;
    }
    #pragma unroll
    for (int sh=1; sh<64; sh<<=1){
      a0 += __shfl_xor(a0,sh,64); a1 += __shfl_xor(a1,sh,64); a2 += __shfl_xor(a2,sh,64); a3 += __shfl_xor(a3,sh,64);
      a4 += __shfl_xor(a4,sh,64); a5 += __shfl_xor(a5,sh,64); a6 += __shfl_xor(a6,sh,64); a7 += __shfl_xor(a7,sh,64);
    }
    if (lane == 0){
      float lg[8] = {a0+gb[0],a1+gb[1],a2+gb[2],a3+gb[3],a4+gb[4],a5+gb[5],a6+gb[6],a7+gb[7]};
      float mx = lg[0];
      #pragma unroll
      for (int e=1;e<8;e++) mx = fmaxf(mx, lg[e]);
      float pex[8], sum = 0.f;
      #pragma unroll
      for (int e=0;e<8;e++){ pex[e] = __expf(lg[e]-mx); sum += pex[e]; }
      int e0 = 0; float b0v = lg[0];
      #pragma unroll
      for (int e=1;e<8;e++) if (lg[e] > b0v){ b0v = lg[e]; e0 = e; }   // strict > : lowest idx on tie
      int e1 = -1; float b1v = -1e30f;
      #pragma unroll
      for (int e=0;e<8;e++) if (e != e0 && lg[e] > b1v){ b1v = lg[e]; e1 = e; }
      float rr = __expf(b1v - b0v);
      float w0 = 1.f/(1.f+rr), w1 = rr/(1.f+rr);   // = s0/(s0+s1), s1/(s0+s1)
      tok_e[t*2] = e0; tok_e[t*2+1] = e1;
      tok_wt[t*2] = w0; tok_wt[t*2+1] = w1;
      atomicAdd(&pcnt[e0], 1); atomicAdd(&pcnt[e1], 1);
      float isum = 1.f/sum;
      #pragma unroll
      for (int e=0;e<8;e++) atomicAdd(&psum[e], pex[e]*isum);
    }
  }
  __syncthreads();
  if (tid < 8){ atomicAdd(&counts[tid], pcnt[tid]); atomicAdd(&probsum[tid], psum[tid]); }
}

__global__ void offsets_k(const int* __restrict__ counts, int* __restrict__ offsets){
  if (threadIdx.x == 0 && blockIdx.x == 0){
    int o = 0;
    for (int e=0;e<8;e++){ offsets[e] = o; o += counts[e]; }
    offsets[8] = o;
  }
}

__global__ __launch_bounds__(256) void assign_k(const int* __restrict__ tok_e, const int* __restrict__ offsets,
                                                int* __restrict__ cursor, int* __restrict__ slot_tok,
                                                int* __restrict__ tok_slot){
  int t = blockIdx.x*256 + threadIdx.x;
  #pragma unroll
  for (int k2=0;k2<2;k2++){
    int e = tok_e[t*2+k2];
    int pos = atomicAdd(&cursor[e], 1);
    int slot = offsets[e] + pos;
    slot_tok[slot] = t;
    tok_slot[t*2+k2] = slot;
  }
}

__global__ __launch_bounds__(256) void gather_k(const u16* __restrict__ x1b, const int* __restrict__ slot_tok, u16* __restrict__ xg){
  int slot = blockIdx.x*4 + (threadIdx.x >> 6);
  int lane = threadIdx.x & 63;
  int t = slot_tok[slot];
  const u16x8* src = (const u16x8*)(x1b + (size_t)t*1024);
  u16x8* dst = (u16x8*)(xg + (size_t)slot*1024);
  dst[lane] = src[lane];
  dst[lane + 64] = src[lane + 64];
}

__global__ void aux_k(const int* __restrict__ counts, const float* __restrict__ probsum, float* __restrict__ outAux){
  if (threadIdx.x == 0 && blockIdx.x == 0){
    float s = 0.f;
    for (int e=0;e<8;e++){
      float frac = (float)counts[e] * (1.f/16384.f);
      float rw = probsum[e] * (1.f/8192.f);
      s += frac * rw;
    }
    outAux[0] = 8.f * s;
  }
}

} // namespace

extern "C" void kernel_launch(void* const* d_in, const int* in_sizes, int n_in,
                              void* d_out, int out_size, void* d_ws, size_t ws_size,
                              hipStream_t stream)
{
  (void)in_sizes; (void)n_in; (void)out_size;
  const float* x   = (const float*)d_in[0];
  const float* Wq  = (const float*)d_in[1];
  const float* bq  = (const float*)d_in[2];
  const float* Wk  = (const float*)d_in[3];
  const float* bk  = (const float*)d_in[4];
  const float* Wv  = (const float*)d_in[5];
  const float* bv  = (const float*)d_in[6];
  const float* Wo  = (const float*)d_in[7];
  const float* bo  = (const float*)d_in[8];
  const float* g1  = (const float*)d_in[9];
  const float* be1 = (const float*)d_in[10];
  const float* gW  = (const float*)d_in[11];
  const float* gb  = (const float*)d_in[12];
  const float* eW1 = (const float*)d_in[13];
  const float* eb1 = (const float*)d_in[14];
  const float* eW2 = (const float*)d_in[15];
  const float* eb2 = (const float*)d_in[16];
  const float* g2  = (const float*)d_in[17];
  const float* be2 = (const float*)d_in[18];
  float* out = (float*)d_out;

  char* base = (char*)d_ws;
  size_t o = 0;
  auto take = [&](size_t bytes){ size_t r = o; o = (o + bytes + 255) & ~(size_t)255; return r; };
  const size_t SZbf = (size_t)Tc*Dc*2;               // 16 MiB bf16 plane
  size_t o_xhi  = take(SZbf);
  size_t o_xlo  = take(SZbf);
  size_t o_wqh  = take((size_t)3072*1024*2);
  size_t o_wql  = take((size_t)3072*1024*2);
  size_t o_qkvh = take(3*SZbf);
  size_t o_qkvl = take(3*SZbf);
  // region [0, here) is dead after flash: reuse for expert weights
  size_t o_e1t = 0;
  size_t o_e2t = (size_t)Ec*Dc*Fc*2;                 // 64 MiB offset, still inside dead region
  size_t o_woh = take((size_t)1024*1024*2);
  size_t o_wol = take((size_t)1024*1024*2);
  size_t o_att = take((size_t)16512*1024*2);         // attnout hi+lo; later xg (16384+128 slack rows)
  size_t o_y1  = take((size_t)Tc*Dc*4);
  size_t o_x1  = take((size_t)Tc*Dc*4);
  size_t o_x1b = take(SZbf);
  size_t o_h   = take((size_t)16512*Fc*2);
  size_t o_yb  = take((size_t)16512*Dc*2);
  size_t o_ctl = take(1<<20);
  if (ws_size < o) return;   // workspace too small -> fail validation loudly

  int*   counts   = (int*)(base + o_ctl + 0);
  int*   cursor   = (int*)(base + o_ctl + 64);
  int*   offs     = (int*)(base + o_ctl + 128);
  float* probsum  = (float*)(base + o_ctl + 192);
  float* bqkv     = (float*)(base + o_ctl + 1024);
  int*   tok_e    = (int*)(base + o_ctl + 16384);
  float* tok_wt   = (float*)(base + o_ctl + 16384 + 65536);
  int*   tok_slot = (int*)(base + o_ctl + 16384 + 131072);
  int*   slot_tok = (int*)(base + o_ctl + 16384 + 196608);

  hipMemsetAsync(base + o_ctl, 0, 256, stream);
  concat_bias_k<<<dim3(12),dim3(256),0,stream>>>(bq, bk, bv, bqkv);
  split_x_k<<<dim3(4096),dim3(256),0,stream>>>(x, (u16*)(base+o_xhi), (u16*)(base+o_xlo));
  transpose_split_k<<<dim3(32,32,1),dim3(256),0,stream>>>(Wq, (u16*)(base+o_wqh),              (u16*)(base+o_wql),              1024,1024, 0,0);
  transpose_split_k<<<dim3(32,32,1),dim3(256),0,stream>>>(Wk, (u16*)(base+o_wqh)+1024*1024,    (u16*)(base+o_wql)+1024*1024,    1024,1024, 0,0);
  transpose_split_k<<<dim3(32,32,1),dim3(256),0,stream>>>(Wv, (u16*)(base+o_wqh)+2*1024*1024,  (u16*)(base+o_wql)+2*1024*1024,  1024,1024, 0,0);
  transpose_split_k<<<dim3(32,32,1),dim3(256),0,stream>>>(Wo, (u16*)(base+o_woh), (u16*)(base+o_wol), 1024,1024, 0,0);

  gemm_k<0><<<dim3(64,24),dim3(256),0,stream>>>((u16*)(base+o_xhi),(u16*)(base+o_xlo),(u16*)(base+o_wqh),(u16*)(base+o_wql),
      bqkv, nullptr, (u16*)(base+o_qkvh), (u16*)(base+o_qkvl), nullptr, 3072, 1024, 1024, 1024);

  {
    u16* qh = (u16*)(base+o_qkvh); u16* ql = (u16*)(base+o_qkvl);
    flash_k<<<dim3(32,64),dim3(256),0,stream>>>(qh, ql, qh+8388608, ql+8388608, qh+16777216, ql+16777216,
        (u16*)(base+o_att), (u16*)(base+o_att)+8388608);
  }

  // expert weights into the now-dead x/Wqkv/QKV region
  transpose_split_k<<<dim3(32,128,8),dim3(256),0,stream>>>(eW1, (u16*)(base+o_e1t), nullptr, 1024, 4096, (size_t)1024*4096, (size_t)4096*1024);
  transpose_split_k<<<dim3(128,32,8),dim3(256),0,stream>>>(eW2, (u16*)(base+o_e2t), nullptr, 4096, 1024, (size_t)4096*1024, (size_t)1024*4096);

  gemm_k<1><<<dim3(64,8),dim3(256),0,stream>>>((u16*)(base+o_att),(u16*)(base+o_att)+8388608,(u16*)(base+o_woh),(u16*)(base+o_wol),
      bo, (float*)(base+o_y1), nullptr, nullptr, nullptr, 1024, 1024, 1024, 1024);

  ln1_k<<<dim3(8192),dim3(256),0,stream>>>((float*)(base+o_y1), x, g1, be1, (float*)(base+o_x1), (u16*)(base+o_x1b));
  gate_k<<<dim3(256),dim3(256),0,stream>>>((float*)(base+o_x1), gW, gb, tok_e, tok_wt, counts, probsum);
  offsets_k<<<dim3(1),dim3(64),0,stream>>>(counts, offs);
  assign_k<<<dim3(32),dim3(256),0,stream>>>(tok_e, offs, cursor, slot_tok, tok_slot);
  gather_k<<<dim3(4096),dim3(256),0,stream>>>((u16*)(base+o_x1b), slot_tok, (u16*)(base+o_att));

  gemm_k<2><<<dim3(64,32,8),dim3(256),0,stream>>>((u16*)(base+o_att), nullptr, (u16*)(base+o_e1t), nullptr,
      eb1, nullptr, (u16*)(base+o_h), nullptr, offs, 4096, 1024, 1024, 1024);
  gemm_k<3><<<dim3(64,8,8),dim3(256),0,stream>>>((u16*)(base+o_h), nullptr, (u16*)(base+o_e2t), nullptr,
      eb2, nullptr, (u16*)(base+o_yb), nullptr, offs, 1024, 4096, 4096, 4096);

  ln2_k<<<dim3(8192),dim3(256),0,stream>>>((float*)(base+o_x1), (u16*)(base+o_yb), tok_slot, tok_wt, g2, be2, out);
  aux_k<<<dim3(1),dim3(64),0,stream>>>(counts, probsum, out + (size_t)Tc*Dc);
}

// Round 2
// 1976.690 us; speedup vs baseline: 1.0773x; 1.0773x over previous
//
#include <hip/hip_runtime.h>
#include <math.h>

typedef unsigned short u16;
typedef unsigned int u32;
typedef __attribute__((ext_vector_type(8))) u16 u16x8;
typedef __attribute__((ext_vector_type(8))) __bf16 b16x8;
typedef __attribute__((ext_vector_type(4))) float f32x4;

#define DEV __device__ __forceinline__

namespace {

constexpr int Tc = 8192, Dc = 1024, Fc = 4096, Ec = 8;

DEV u16 f2bf(float f){ union{float f; unsigned u;} v; v.f=f; unsigned r = v.u + 0x7fffu + ((v.u>>16)&1u); return (u16)(r>>16); }
DEV float bf2f(u16 h){ union{unsigned u; float f;} v; v.u=((unsigned)h)<<16; return v.f; }
DEV f32x4 zero4(){ f32x4 z = {0.f,0.f,0.f,0.f}; return z; }
DEV f32x4 mfma16(u16x8 a, u16x8 b, f32x4 c){
  union { u16x8 u; b16x8 b; } ua, ub; ua.u = a; ub.u = b;
  return __builtin_amdgcn_mfma_f32_16x16x32_bf16(ua.b, ub.b, c, 0, 0, 0);
}
DEV float gelu_exact(float v){ return 0.5f*v*(1.0f + erff(v*0.70710678118654752f)); }

typedef __attribute__((address_space(1))) const unsigned GU;
typedef __attribute__((address_space(3))) unsigned LU;
// async global->LDS, 16B per lane; LDS dest = wave-uniform base + lane*16
DEV void cp16(const u16* g, u16* l){
  __builtin_amdgcn_global_load_lds((GU*)g, (LU*)l, 16, 0, 0);
}

// ---------------- prep kernels ----------------
__global__ __launch_bounds__(256) void split_x_k(const float* __restrict__ x, u16* __restrict__ hi, u16* __restrict__ lo){
  size_t i = (size_t)blockIdx.x*256 + threadIdx.x;
  #pragma unroll
  for (int r=0;r<8;r++){
    size_t idx = i + (size_t)r*1048576;
    float v = x[idx];
    u16 h = f2bf(v);
    hi[idx] = h;
    lo[idx] = f2bf(v - bf2f(h));
  }
}

__global__ __launch_bounds__(256) void concat_bias_k(const float* __restrict__ bq, const float* __restrict__ bk,
                                                     const float* __restrict__ bv, float* __restrict__ dst){
  int n = blockIdx.x*256 + threadIdx.x;
  if (n < 3072) dst[n] = (n<1024) ? bq[n] : ((n<2048) ? bk[n-1024] : bv[n-2048]);
}

// W[Kd][Nd] f32 -> out[Nd][Kd] bf16 hi (+lo if oLo)
__global__ __launch_bounds__(256) void transpose_split_k(const float* __restrict__ W, u16* __restrict__ oHi, u16* __restrict__ oLo,
                                                         int Kd, int Nd, size_t inStride, size_t outStride){
  __shared__ float t[32][33];
  int e = blockIdx.z;
  W += (size_t)e*inStride; oHi += (size_t)e*outStride; if (oLo) oLo += (size_t)e*outStride;
  int k0 = blockIdx.x*32, n0 = blockIdx.y*32;
  int c = threadIdx.x & 31, r0 = threadIdx.x >> 5;
  #pragma unroll
  for (int i=0;i<4;i++){ int r = r0 + i*8; t[r][c] = W[(size_t)(k0+r)*Nd + n0 + c]; }
  __syncthreads();
  #pragma unroll
  for (int i=0;i<4;i++){
    int r = r0 + i*8;
    float v = t[c][r];                    // = W[k0+c][n0+r]
    size_t oidx = (size_t)(n0+r)*Kd + k0 + c;
    u16 h = f2bf(v);
    oHi[oidx] = h;
    if (oLo) oLo[oidx] = f2bf(v - bf2f(h));
  }
}

// ---------------- GEMM: C[M][N] = A[M][K] @ Bt[N][K]^T ----------------
// m97 structure: BK=32, unpadded pitch-32 LDS, global_load_lds width=16 staging.
// MODE 0: QKV (x3-plane, bias, scatter Q/K->[bh][s][d], V->[bh][d][s], hi/lo out)
// MODE 1: out-proj (x3, bias, f32 out)
// MODE 2: FF1 per-expert (bf16, bias+gelu, bf16 out)
// MODE 3: FF2 per-expert (bf16, bias, bf16 out)
template<int MODE>
__global__ __launch_bounds__(256,2) void gemm_k(
    const u16* __restrict__ Ahi, const u16* __restrict__ Alo,
    const u16* __restrict__ Bhi, const u16* __restrict__ Blo,
    const float* __restrict__ bias,
    float* __restrict__ outF, u16* __restrict__ outHi, u16* __restrict__ outLo,
    const int* __restrict__ offsets,
    int N, int K, int lda, int ldb)
{
  constexpr bool X3 = (MODE <= 1);
  constexpr int PL = X3 ? 2 : 1;
  int Me = 0, rowbase = 0;
  if constexpr (MODE >= 2){
    int e = blockIdx.z;
    rowbase = offsets[e];
    Me = offsets[e+1] - rowbase;
    if ((int)blockIdx.x*128 >= Me) return;     // uniform early exit
    Ahi += (size_t)rowbase * lda;
    Bhi += (size_t)e * N * K;
    bias += (size_t)e * N;
  }
  __shared__ u16 sA[PL][128*32];   // pitch 32 (contiguous; required by global_load_lds)
  __shared__ u16 sB[PL][128*32];
  const int tid = threadIdx.x;
  const int lane = tid & 63, wid = tid >> 6;
  const int l15 = lane & 15, l4 = lane >> 4;
  const int mh = (wid >> 1) * 64, nh = (wid & 1) * 64;
  const int bm = blockIdx.x, bn = blockIdx.y;
  const int srow = lane >> 2;          // staging row within 16-row chunk
  const int sk8  = (lane & 3) * 8;     // staging k-offset (u16)

  f32x4 acc[4][4];
  #pragma unroll
  for (int i=0;i<4;i++)
    #pragma unroll
    for (int j=0;j<4;j++) acc[i][j] = zero4();

  const int nK = K >> 5;
  for (int kb=0; kb<nK; ++kb){
    const int k0 = kb << 5;
    __syncthreads();
    #pragma unroll
    for (int c=0;c<2;c++){
      int chunk = wid*2 + c;                  // 8 chunks of 16 rows
      int row = chunk*16 + srow;
      size_t ga = (size_t)(bm*128 + row)*lda + k0 + sk8;
      size_t gb = (size_t)(bn*128 + row)*ldb + k0 + sk8;
      cp16(Ahi + ga, &sA[0][chunk*512]);
      cp16(Bhi + gb, &sB[0][chunk*512]);
      if constexpr (X3){
        cp16(Alo + ga, &sA[1][chunk*512]);
        cp16(Blo + gb, &sB[1][chunk*512]);
      }
    }
    __syncthreads();
    u16x8 af[PL][4], bfr[PL][4];
    #pragma unroll
    for (int mt=0;mt<4;mt++){
      int ra = (mh + mt*16 + l15)*32 + l4*8;
      int rb = (nh + mt*16 + l15)*32 + l4*8;
      af[0][mt]  = *(const u16x8*)&sA[0][ra];
      bfr[0][mt] = *(const u16x8*)&sB[0][rb];
      if constexpr (X3){ af[1][mt] = *(const u16x8*)&sA[1][ra]; bfr[1][mt] = *(const u16x8*)&sB[1][rb]; }
    }
    #pragma unroll
    for (int mt=0;mt<4;mt++)
      #pragma unroll
      for (int nt=0;nt<4;nt++){
        acc[mt][nt] = mfma16(af[0][mt], bfr[0][nt], acc[mt][nt]);
        if constexpr (X3){
          acc[mt][nt] = mfma16(af[0][mt], bfr[1][nt], acc[mt][nt]);   // hi*lo
          acc[mt][nt] = mfma16(af[1][mt], bfr[0][nt], acc[mt][nt]);   // lo*hi
        }
      }
  }
  #pragma unroll
  for (int mt=0;mt<4;mt++)
    #pragma unroll
    for (int nt=0;nt<4;nt++)
      #pragma unroll
      for (int r=0;r<4;r++){
        int m = bm*128 + mh + mt*16 + l4*4 + r;     // C/D: row=(lane>>4)*4+reg
        int n = bn*128 + nh + nt*16 + l15;          //      col=lane&15
        float v = acc[mt][nt][r];
        if constexpr (MODE == 0){
          v += bias[n];
          int which = n >> 10, h = (n >> 6) & 15, d = n & 63;
          int b = m >> 11, s = m & 2047;
          size_t idx;
          if (which == 2)   // V stored transposed: [bh][d][s]
            idx = ((((size_t)2*4 + b)*16 + h)*64 + d)*2048 + s;
          else
            idx = ((((size_t)which*4 + b)*16 + h)*2048 + s)*64 + d;
          u16 hi = f2bf(v);
          outHi[idx] = hi; outLo[idx] = f2bf(v - bf2f(hi));
        } else if constexpr (MODE == 1){
          outF[(size_t)m*1024 + n] = v + bias[n];
        } else if constexpr (MODE == 2){
          if (m < Me){
            float g = gelu_exact(v + bias[n]);
            outHi[(size_t)(rowbase + m)*N + n] = f2bf(g);
          }
        } else {
          if (m < Me){
            outHi[(size_t)(rowbase + m)*N + n] = f2bf(v + bias[n]);
          }
        }
      }
}

// ---------------- flash attention, bf16x3 ----------------
// grid (S/128, B*H); block 256 = 4 waves; wave owns 32 q-rows (2 m-subtiles); KV tile 64.
// V arrives pre-transposed [bh][d][s]. P packed hi|lo<<16 in u32 LDS (pitch 68: conflict-free writes).
__global__ __launch_bounds__(256,2) void flash_k(
    const u16* __restrict__ qhi, const u16* __restrict__ qlo,
    const u16* __restrict__ khi, const u16* __restrict__ klo,
    const u16* __restrict__ vthi, const u16* __restrict__ vtlo,
    u16* __restrict__ ohi, u16* __restrict__ olo)
{
  __shared__ u16 Kl[2][64*72];     // [plane][kk][d] pitch 72
  __shared__ u16 Vt[2][64*72];     // [plane][d][kk] pitch 72 (from global V^T)
  __shared__ u32 Pint[128*68];     // [q][kk] packed hi|lo<<16, pitch 68 u32
  const int qt = blockIdx.x, bh = blockIdx.y;
  const int b = bh >> 4, h = bh & 15;
  const int tid = threadIdx.x, wid = tid >> 6, lane = tid & 63;
  const int l15 = lane & 15, l4 = lane >> 4;
  const size_t bhBase = (size_t)bh * (2048*64);

  u16x8 qf[2][2][2];               // [mi][plane][kstep]
  #pragma unroll
  for (int mi=0;mi<2;mi++)
    #pragma unroll
    for (int ks=0;ks<2;ks++){
      size_t po = bhBase + (size_t)(qt*128 + wid*32 + mi*16 + l15)*64 + ks*32 + l4*8;
      qf[mi][0][ks] = *(const u16x8*)(qhi + po);
      qf[mi][1][ks] = *(const u16x8*)(qlo + po);
    }
  f32x4 O[2][4];
  #pragma unroll
  for (int mi=0;mi<2;mi++)
    #pragma unroll
    for (int nd=0;nd<4;nd++) O[mi][nd] = zero4();
  float mrow[2][4], lrow[2][4];
  #pragma unroll
  for (int mi=0;mi<2;mi++)
    #pragma unroll
    for (int r=0;r<4;r++){ mrow[mi][r] = -1e30f; lrow[mi][r] = 0.f; }

  for (int t=0;t<32;++t){
    __syncthreads();                              // prior-iter LDS reads done before restage
    const size_t kBase = bhBase + (size_t)t*(64*64);
    #pragma unroll
    for (int pl=0; pl<2; ++pl){
      const u16* kp = pl ? klo : khi;
      const u16* vp = pl ? vtlo : vthi;
      #pragma unroll
      for (int r2=0;r2<2;r2++){
        int c = tid + r2*256;                     // 512 chunks of 16B
        int rr = c >> 3, c8 = (c & 7) * 8;
        *(u16x8*)&Kl[pl][rr*72 + c8] = *(const u16x8*)(kp + kBase + (size_t)rr*64 + c8);
        *(u16x8*)&Vt[pl][rr*72 + c8] = *(const u16x8*)(vp + bhBase + (size_t)rr*2048 + t*64 + c8);
      }
    }
    __syncthreads();

    // K fragments for all 4 n-subtiles, held in regs across both m-subtiles
    u16x8 kf[4][2][2];
    #pragma unroll
    for (int nt=0;nt<4;nt++)
      #pragma unroll
      for (int pl=0;pl<2;pl++)
        #pragma unroll
        for (int ks=0;ks<2;ks++)
          kf[nt][pl][ks] = *(const u16x8*)&Kl[pl][(nt*16 + l15)*72 + ks*32 + l4*8];

    #pragma unroll
    for (int mi=0;mi<2;mi++){
      f32x4 sc[4];
      #pragma unroll
      for (int nt=0;nt<4;nt++){
        f32x4 a = zero4();
        a = mfma16(qf[mi][0][0], kf[nt][0][0], a);
        a = mfma16(qf[mi][0][1], kf[nt][0][1], a);
        a = mfma16(qf[mi][0][0], kf[nt][1][0], a);
        a = mfma16(qf[mi][0][1], kf[nt][1][1], a);
        a = mfma16(qf[mi][1][0], kf[nt][0][0], a);
        a = mfma16(qf[mi][1][1], kf[nt][0][1], a);
        sc[nt] = a;
      }
      float alpha[4];
      #pragma unroll
      for (int r=0;r<4;r++){
        float mx = -1e30f;
        #pragma unroll
        for (int nt=0;nt<4;nt++){ sc[nt][r] *= 0.125f; mx = fmaxf(mx, sc[nt][r]); }
        #pragma unroll
        for (int sh=1; sh<16; sh<<=1) mx = fmaxf(mx, __shfl_xor(mx, sh, 64));
        float mn = fmaxf(mrow[mi][r], mx);
        alpha[r] = __expf(mrow[mi][r] - mn);
        mrow[mi][r] = mn;
        float ls = 0.f;
        #pragma unroll
        for (int nt=0;nt<4;nt++){
          float p = __expf(sc[nt][r] - mn);
          sc[nt][r] = p;
          ls += p;
        }
        #pragma unroll
        for (int sh=1; sh<16; sh<<=1) ls += __shfl_xor(ls, sh, 64);
        lrow[mi][r] = lrow[mi][r]*alpha[r] + ls;
      }
      // packed P write: banks = l4*16 + l15 (mod 32) -> exact 2-way, free
      #pragma unroll
      for (int nt=0;nt<4;nt++)
        #pragma unroll
        for (int r=0;r<4;r++){
          int row = wid*32 + mi*16 + l4*4 + r;
          int col = nt*16 + l15;
          float p = sc[nt][r];
          u16 hi = f2bf(p);
          u16 lo = f2bf(p - bf2f(hi));
          Pint[row*68 + col] = (u32)hi | ((u32)lo << 16);
        }
      #pragma unroll
      for (int nd=0;nd<4;nd++)
        #pragma unroll
        for (int r=0;r<4;r++) O[mi][nd][r] *= alpha[r];
    }

    // read P back in A-layout (b128 + v_perm extraction)
    u16x8 pf[2][2][2];               // [mi][plane][ks]
    #pragma unroll
    for (int mi=0;mi<2;mi++)
      #pragma unroll
      for (int ks=0;ks<2;ks++){
        const u32* pr = &Pint[(wid*32 + mi*16 + l15)*68 + ks*32 + l4*8];
        uint4 c0 = *(const uint4*)pr;
        uint4 c1 = *(const uint4*)(pr + 4);
        union { u16x8 v; u32 u[4]; } ph, pl2;
        ph.u[0]  = __builtin_amdgcn_perm(c0.y, c0.x, 0x05040100u);
        ph.u[1]  = __builtin_amdgcn_perm(c0.w, c0.z, 0x05040100u);
        ph.u[2]  = __builtin_amdgcn_perm(c1.y, c1.x, 0x05040100u);
        ph.u[3]  = __builtin_amdgcn_perm(c1.w, c1.z, 0x05040100u);
        pl2.u[0] = __builtin_amdgcn_perm(c0.y, c0.x, 0x07060302u);
        pl2.u[1] = __builtin_amdgcn_perm(c0.w, c0.z, 0x07060302u);
        pl2.u[2] = __builtin_amdgcn_perm(c1.y, c1.x, 0x07060302u);
        pl2.u[3] = __builtin_amdgcn_perm(c1.w, c1.z, 0x07060302u);
        pf[mi][0][ks] = ph.v;
        pf[mi][1][ks] = pl2.v;
      }
    #pragma unroll
    for (int nd=0;nd<4;nd++){
      u16x8 vf[2][2];
      #pragma unroll
      for (int pl=0;pl<2;pl++)
        #pragma unroll
        for (int ks=0;ks<2;ks++)
          vf[pl][ks] = *(const u16x8*)&Vt[pl][(nd*16 + l15)*72 + ks*32 + l4*8];
      #pragma unroll
      for (int mi=0;mi<2;mi++){
        f32x4 a = O[mi][nd];
        a = mfma16(pf[mi][0][0], vf[0][0], a);
        a = mfma16(pf[mi][0][1], vf[0][1], a);
        a = mfma16(pf[mi][0][0], vf[1][0], a);
        a = mfma16(pf[mi][0][1], vf[1][1], a);
        a = mfma16(pf[mi][1][0], vf[0][0], a);
        a = mfma16(pf[mi][1][1], vf[0][1], a);
        O[mi][nd] = a;
      }
    }
  }
  #pragma unroll
  for (int mi=0;mi<2;mi++)
    #pragma unroll
    for (int nd=0;nd<4;nd++)
      #pragma unroll
      for (int r=0;r<4;r++){
        int srow = qt*128 + wid*32 + mi*16 + l4*4 + r;
        int d = nd*16 + l15;
        float v = O[mi][nd][r] / lrow[mi][r];
        size_t idx = ((size_t)b*2048 + srow)*1024 + h*64 + d;   // [B,S,H*64] token-major
        u16 hi = f2bf(v);
        ohi[idx] = hi; olo[idx] = f2bf(v - bf2f(hi));
      }
}

// ---------------- LayerNorms ----------------
__global__ __launch_bounds__(256) void ln1_k(const float* __restrict__ y1, const float* __restrict__ x,
                                             const float* __restrict__ g, const float* __restrict__ be,
                                             float* __restrict__ x1, u16* __restrict__ x1b){
  __shared__ float red[2][4];
  int t = blockIdx.x, tid = threadIdx.x;
  const float* yr = y1 + (size_t)t*1024;
  const float* xr = x + (size_t)t*1024;
  float v[4], s = 0.f, s2 = 0.f;
  #pragma unroll
  for (int i=0;i<4;i++){ int d = tid + i*256; v[i] = yr[d] + xr[d]; s += v[i]; s2 += v[i]*v[i]; }
  #pragma unroll
  for (int sh=1; sh<64; sh<<=1){ s += __shfl_xor(s, sh, 64); s2 += __shfl_xor(s2, sh, 64); }
  int wid = tid >> 6, lane = tid & 63;
  if (lane == 0){ red[0][wid] = s; red[1][wid] = s2; }
  __syncthreads();
  s  = red[0][0]+red[0][1]+red[0][2]+red[0][3];
  s2 = red[1][0]+red[1][1]+red[1][2]+red[1][3];
  float mu = s * (1.f/1024.f);
  float var = s2 * (1.f/1024.f) - mu*mu;
  float inv = 1.0f / sqrtf(var + 1e-5f);
  #pragma unroll
  for (int i=0;i<4;i++){
    int d = tid + i*256;
    float o2 = (v[i]-mu)*inv*g[d] + be[d];
    x1[(size_t)t*1024 + d] = o2;
    x1b[(size_t)t*1024 + d] = f2bf(o2);
  }
}

__global__ __launch_bounds__(256) void ln2_k(const float* __restrict__ x1, const u16* __restrict__ ybuf,
                                             const int* __restrict__ tok_slot, const float* __restrict__ tok_wt,
                                             const float* __restrict__ g, const float* __restrict__ be,
                                             float* __restrict__ out){
  __shared__ float red[2][4];
  int t = blockIdx.x, tid = threadIdx.x;
  int s0 = tok_slot[t*2], s1 = tok_slot[t*2+1];
  float w0 = tok_wt[t*2], w1 = tok_wt[t*2+1];
  const float* xr = x1 + (size_t)t*1024;
  const u16* y0 = ybuf + (size_t)s0*1024;
  const u16* y1p = ybuf + (size_t)s1*1024;
  float v[4], s = 0.f, s2 = 0.f;
  #pragma unroll
  for (int i=0;i<4;i++){
    int d = tid + i*256;
    v[i] = xr[d] + w0*bf2f(y0[d]) + w1*bf2f(y1p[d]);
    s += v[i]; s2 += v[i]*v[i];
  }
  #pragma unroll
  for (int sh=1; sh<64; sh<<=1){ s += __shfl_xor(s, sh, 64); s2 += __shfl_xor(s2, sh, 64); }
  int wid = tid >> 6, lane = tid & 63;
  if (lane == 0){ red[0][wid] = s; red[1][wid] = s2; }
  __syncthreads();
  s  = red[0][0]+red[0][1]+red[0][2]+red[0][3];
  s2 = red[1][0]+red[1][1]+red[1][2]+red[1][3];
  float mu = s * (1.f/1024.f);
  float var = s2 * (1.f/1024.f) - mu*mu;
  float inv = 1.0f / sqrtf(var + 1e-5f);
  #pragma unroll
  for (int i=0;i<4;i++){
    int d = tid + i*256;
    out[(size_t)t*1024 + d] = (v[i]-mu)*inv*g[d] + be[d];
  }
}

// ---------------- routing ----------------
__global__ __launch_bounds__(256) void gate_k(const float* __restrict__ x1, const float* __restrict__ gW, const float* __restrict__ gb,
                                              int* __restrict__ tok_e, float* __restrict__ tok_wt,
                                              int* __restrict__ counts, float* __restrict__ probsum){
  __shared__ float psum[8];
  __shared__ int pcnt[8];
  int tid = threadIdx.x, wid = tid>>6, lane = tid&63;
  if (tid < 8){ psum[tid] = 0.f; pcnt[tid] = 0; }
  __syncthreads();
  for (int it=0; it<8; ++it){
    int t = blockIdx.x*32 + wid*8 + it;
    const float* xr = x1 + (size_t)t*1024;
    float a0=0,a1=0,a2=0,a3=0,a4=0,a5=0,a6=0,a7=0;
    #pragma unroll
    for (int j=0;j<16;j++){
      int i = lane + j*64;
      float xv = xr[i];
      const float4* w4 = (const float4*)(gW + (size_t)i*8);
      float4 wa = w4[0], wb = w4[1];
      a0 += xv*wa.x; a1 += xv*wa.y; a2 += xv*wa.z; a3 += xv*wa.w;
      a4 += xv*wb.x; a5 += xv*wb.y; a6 += xv*wb.z; a7 += xv*wb.w;
    }
    #pragma unroll
    for (int sh=1; sh<64; sh<<=1){
      a0 += __shfl_xor(a0,sh,64); a1 += __shfl_xor(a1,sh,64); a2 += __shfl_xor(a2,sh,64); a3 += __shfl_xor(a3,sh,64);
      a4 += __shfl_xor(a4,sh,64); a5 += __shfl_xor(a5,sh,64); a6 += __shfl_xor(a6,sh,64); a7 += __shfl_xor(a7,sh,64);
    }
    if (lane == 0){
      float lg[8] = {a0+gb[0],a1+gb[1],a2+gb[2],a3+gb[3],a4+gb[4],a5+gb[5],a6+gb[6],a7+gb[7]};
      float mx = lg[0];
      #pragma unroll
      for (int e=1;e<8;e++) mx = fmaxf(mx, lg[e]);
      float pex[8], sum = 0.f;
      #pragma unroll
      for (int e=0;e<8;e++){ pex[e] = __expf(lg[e]-mx); sum += pex[e]; }
      int e0 = 0; float b0v = lg[0];
      #pragma unroll
      for (int e=1;e<8;e++) if (lg[e] > b0v){ b0v = lg[e]; e0 = e; }   // strict > : lowest idx on tie
      int e1 = -1; float b1v = -1e30f;
      #pragma unroll
      for (int e=0;e<8;e++) if (e != e0 && lg[e] > b1v){ b1v = lg[e]; e1 = e; }
      float rr = __expf(b1v - b0v);
      float w0 = 1.f/(1.f+rr), w1 = rr/(1.f+rr);   // = s0/(s0+s1), s1/(s0+s1)
      tok_e[t*2] = e0; tok_e[t*2+1] = e1;
      tok_wt[t*2] = w0; tok_wt[t*2+1] = w1;
      atomicAdd(&pcnt[e0], 1); atomicAdd(&pcnt[e1], 1);
      float isum = 1.f/sum;
      #pragma unroll
      for (int e=0;e<8;e++) atomicAdd(&psum[e], pex[e]*isum);
    }
  }
  __syncthreads();
  if (tid < 8){ atomicAdd(&counts[tid], pcnt[tid]); atomicAdd(&probsum[tid], psum[tid]); }
}

__global__ void offsets_k(const int* __restrict__ counts, int* __restrict__ offsets){
  if (threadIdx.x == 0 && blockIdx.x == 0){
    int o = 0;
    for (int e=0;e<8;e++){ offsets[e] = o; o += counts[e]; }
    offsets[8] = o;
  }
}

__global__ __launch_bounds__(256) void assign_k(const int* __restrict__ tok_e, const int* __restrict__ offsets,
                                                int* __restrict__ cursor, int* __restrict__ slot_tok,
                                                int* __restrict__ tok_slot){
  int t = blockIdx.x*256 + threadIdx.x;
  #pragma unroll
  for (int k2=0;k2<2;k2++){
    int e = tok_e[t*2+k2];
    int pos = atomicAdd(&cursor[e], 1);
    int slot = offsets[e] + pos;
    slot_tok[slot] = t;
    tok_slot[t*2+k2] = slot;
  }
}

__global__ __launch_bounds__(256) void gather_k(const u16* __restrict__ x1b, const int* __restrict__ slot_tok, u16* __restrict__ xg){
  int slot = blockIdx.x*4 + (threadIdx.x >> 6);
  int lane = threadIdx.x & 63;
  int t = slot_tok[slot];
  const u16x8* src = (const u16x8*)(x1b + (size_t)t*1024);
  u16x8* dst = (u16x8*)(xg + (size_t)slot*1024);
  dst[lane] = src[lane];
  dst[lane + 64] = src[lane + 64];
}

__global__ void aux_k(const int* __restrict__ counts, const float* __restrict__ probsum, float* __restrict__ outAux){
  if (threadIdx.x == 0 && blockIdx.x == 0){
    float s = 0.f;
    for (int e=0;e<8;e++){
      float frac = (float)counts[e] * (1.f/16384.f);
      float rw = probsum[e] * (1.f/8192.f);
      s += frac * rw;
    }
    outAux[0] = 8.f * s;
  }
}

} // namespace

extern "C" void kernel_launch(void* const* d_in, const int* in_sizes, int n_in,
                              void* d_out, int out_size, void* d_ws, size_t ws_size,
                              hipStream_t stream)
{
  (void)in_sizes; (void)n_in; (void)out_size;
  const float* x   = (const float*)d_in[0];
  const float* Wq  = (const float*)d_in[1];
  const float* bq  = (const float*)d_in[2];
  const float* Wk  = (const float*)d_in[3];
  const float* bk  = (const float*)d_in[4];
  const float* Wv  = (const float*)d_in[5];
  const float* bv  = (const float*)d_in[6];
  const float* Wo  = (const float*)d_in[7];
  const float* bo  = (const float*)d_in[8];
  const float* g1  = (const float*)d_in[9];
  const float* be1 = (const float*)d_in[10];
  const float* gW  = (const float*)d_in[11];
  const float* gb  = (const float*)d_in[12];
  const float* eW1 = (const float*)d_in[13];
  const float* eb1 = (const float*)d_in[14];
  const float* eW2 = (const float*)d_in[15];
  const float* eb2 = (const float*)d_in[16];
  const float* g2  = (const float*)d_in[17];
  const float* be2 = (const float*)d_in[18];
  float* out = (float*)d_out;

  char* base = (char*)d_ws;
  size_t o = 0;
  auto take = [&](size_t bytes){ size_t r = o; o = (o + bytes + 255) & ~(size_t)255; return r; };
  const size_t SZbf = (size_t)Tc*Dc*2;               // 16 MiB bf16 plane
  size_t o_xhi  = take(SZbf);
  size_t o_xlo  = take(SZbf);
  size_t o_wqh  = take((size_t)3072*1024*2);
  size_t o_wql  = take((size_t)3072*1024*2);
  size_t o_qkvh = take(3*SZbf);
  size_t o_qkvl = take(3*SZbf);
  // region [0, here) is dead after flash: reuse for expert weights
  size_t o_e1t = 0;
  size_t o_e2t = (size_t)Ec*Dc*Fc*2;                 // 64 MiB offset, still inside dead region
  size_t o_woh = take((size_t)1024*1024*2);
  size_t o_wol = take((size_t)1024*1024*2);
  size_t o_att = take((size_t)16512*1024*2);         // attnout hi+lo; later xg (16384+128 slack rows)
  size_t o_y1  = take((size_t)Tc*Dc*4);
  size_t o_x1  = take((size_t)Tc*Dc*4);
  size_t o_x1b = take(SZbf);
  size_t o_h   = take((size_t)16512*Fc*2);
  size_t o_yb  = take((size_t)16512*Dc*2);
  size_t o_ctl = take(1<<20);
  if (ws_size < o) return;   // workspace too small -> fail validation loudly

  int*   counts   = (int*)(base + o_ctl + 0);
  int*   cursor   = (int*)(base + o_ctl + 64);
  int*   offs     = (int*)(base + o_ctl + 128);
  float* probsum  = (float*)(base + o_ctl + 192);
  float* bqkv     = (float*)(base + o_ctl + 1024);
  int*   tok_e    = (int*)(base + o_ctl + 16384);
  float* tok_wt   = (float*)(base + o_ctl + 16384 + 65536);
  int*   tok_slot = (int*)(base + o_ctl + 16384 + 131072);
  int*   slot_tok = (int*)(base + o_ctl + 16384 + 196608);

  hipMemsetAsync(base + o_ctl, 0, 256, stream);
  concat_bias_k<<<dim3(12),dim3(256),0,stream>>>(bq, bk, bv, bqkv);
  split_x_k<<<dim3(4096),dim3(256),0,stream>>>(x, (u16*)(base+o_xhi), (u16*)(base+o_xlo));
  transpose_split_k<<<dim3(32,32,1),dim3(256),0,stream>>>(Wq, (u16*)(base+o_wqh),              (u16*)(base+o_wql),              1024,1024, 0,0);
  transpose_split_k<<<dim3(32,32,1),dim3(256),0,stream>>>(Wk, (u16*)(base+o_wqh)+1024*1024,    (u16*)(base+o_wql)+1024*1024,    1024,1024, 0,0);
  transpose_split_k<<<dim3(32,32,1),dim3(256),0,stream>>>(Wv, (u16*)(base+o_wqh)+2*1024*1024,  (u16*)(base+o_wql)+2*1024*1024,  1024,1024, 0,0);
  transpose_split_k<<<dim3(32,32,1),dim3(256),0,stream>>>(Wo, (u16*)(base+o_woh), (u16*)(base+o_wol), 1024,1024, 0,0);

  gemm_k<0><<<dim3(64,24),dim3(256),0,stream>>>((u16*)(base+o_xhi),(u16*)(base+o_xlo),(u16*)(base+o_wqh),(u16*)(base+o_wql),
      bqkv, nullptr, (u16*)(base+o_qkvh), (u16*)(base+o_qkvl), nullptr, 3072, 1024, 1024, 1024);

  {
    u16* qh = (u16*)(base+o_qkvh); u16* ql = (u16*)(base+o_qkvl);
    flash_k<<<dim3(16,64),dim3(256),0,stream>>>(qh, ql, qh+8388608, ql+8388608, qh+16777216, ql+16777216,
        (u16*)(base+o_att), (u16*)(base+o_att)+8388608);
  }

  // expert weights into the now-dead x/Wqkv/QKV region
  transpose_split_k<<<dim3(32,128,8),dim3(256),0,stream>>>(eW1, (u16*)(base+o_e1t), nullptr, 1024, 4096, (size_t)1024*4096, (size_t)4096*1024);
  transpose_split_k<<<dim3(128,32,8),dim3(256),0,stream>>>(eW2, (u16*)(base+o_e2t), nullptr, 4096, 1024, (size_t)4096*1024, (size_t)1024*4096);

  gemm_k<1><<<dim3(64,8),dim3(256),0,stream>>>((u16*)(base+o_att),(u16*)(base+o_att)+8388608,(u16*)(base+o_woh),(u16*)(base+o_wol),
      bo, (float*)(base+o_y1), nullptr, nullptr, nullptr, 1024, 1024, 1024, 1024);

  ln1_k<<<dim3(8192),dim3(256),0,stream>>>((float*)(base+o_y1), x, g1, be1, (float*)(base+o_x1), (u16*)(base+o_x1b));
  gate_k<<<dim3(256),dim3(256),0,stream>>>((float*)(base+o_x1), gW, gb, tok_e, tok_wt, counts, probsum);
  offsets_k<<<dim3(1),dim3(64),0,stream>>>(counts, offs);
  assign_k<<<dim3(32),dim3(256),0,stream>>>(tok_e, offs, cursor, slot_tok, tok_slot);
  gather_k<<<dim3(4096),dim3(256),0,stream>>>((u16*)(base+o_x1b), slot_tok, (u16*)(base+o_att));

  gemm_k<2><<<dim3(64,32,8),dim3(256),0,stream>>>((u16*)(base+o_att), nullptr, (u16*)(base+o_e1t), nullptr,
      eb1, nullptr, (u16*)(base+o_h), nullptr, offs, 4096, 1024, 1024, 1024);
  gemm_k<3><<<dim3(64,8,8),dim3(256),0,stream>>>((u16*)(base+o_h), nullptr, (u16*)(base+o_e2t), nullptr,
      eb2, nullptr, (u16*)(base+o_yb), nullptr, offs, 1024, 4096, 4096, 4096);

  ln2_k<<<dim3(8192),dim3(256),0,stream>>>((float*)(base+o_x1), (u16*)(base+o_yb), tok_slot, tok_wt, g2, be2, out);
  aux_k<<<dim3(1),dim3(64),0,stream>>>(counts, probsum, out + (size_t)Tc*Dc);
}